// Round 9
// baseline (868.144 us; speedup 1.0000x reference)
//
#include <hip/hip_runtime.h>

typedef float v2f __attribute__((ext_vector_type(2)));
typedef float v4f __attribute__((ext_vector_type(4)));
typedef short bh8 __attribute__((ext_vector_type(8)));   // 8 bf16 in 4 VGPRs

#define N_IN   131072
#define K_EMB  1024
#define D_EMB  64
#define QUANT_OFF 1
#define PERP_OFF  (1 + N_IN * D_EMB)      /* 8388609 */
#define ENC_OFF   (PERP_OFF + 1)          /* 8388610: byte offset %16==8 -> float2 stores only */
#define EPS_GAP 0.01f

// ws float layout:
//   [0..1023]       counts (u32)
//   [1024]          loss accumulator (f32)
//   [2048..3071]    hn = 0.5*||e||^2 (f32, fp64-accumulated)
//   [4096..36863]   e_hi bf16[1024*64] (128 KB)
//   [36864..69631]  e_lo bf16[1024*64] (128 KB)
#define EHI_F 4096
#define ELO_F 36864

__device__ __forceinline__ unsigned short f2bf_rn(float f) {
  unsigned u = __float_as_uint(f);
  return (unsigned short)((u + 0x7FFFu + ((u >> 16) & 1u)) >> 16);
}

__global__ __launch_bounds__(256) void k_prep(const float* __restrict__ emb,
                                              float* __restrict__ ws) {
  int k = blockIdx.x * 256 + threadIdx.x;  // grid=4 -> k in [0,1024)
  ((unsigned int*)ws)[k] = 0u;
  if (k == 0) ws[1024] = 0.0f;
  unsigned short* ehi = (unsigned short*)(ws + EHI_F);
  unsigned short* elo = (unsigned short*)(ws + ELO_F);
  const float* e = emb + (size_t)k * D_EMB;
  double s = 0.0;
  #pragma unroll
  for (int d = 0; d < D_EMB; ++d) {
    float f = e[d];
    s += (double)f * (double)f;
    unsigned short h = f2bf_rn(f);
    float hf = __uint_as_float((unsigned)h << 16);
    ehi[k * 64 + d] = h;
    elo[k * 64 + d] = f2bf_rn(f - hf);
  }
  ws[2048 + k] = (float)(0.5 * s);
}

// R9: compensated-bf16 MFMA scan + exact-fp32 fixup for near-ties.
// R8 post-mortem: fp32 outer-product is LDS-pipe-bound (~164us/CU floor).
// Here the inner loop has ZERO LDS traffic: A-frags (x hi/lo) in registers,
// B-frags (e hi/lo) as 16B global loads from ws (L2-resident, 256KB total).
// S = x_hi.e_hi + x_lo.e_hi + x_hi.e_lo (lo.lo dropped) -> |err| ~1e-4.
// Track (best, runner-up); gap < EPS_GAP=0.01 -> block rescans that sample
// with R7/R8's exact fp32 arithmetic (expected ~0.2 samples/block).
// MFMA layouts (m89/m91/m120-verified): A[m=lane&15][k=quad*8+j],
// B[n=lane&15][k=quad*8+j], D col=lane&15 (code), row=quad*4+reg (sample).
__global__ __launch_bounds__(256, 2) void k_gemm(const float* __restrict__ xg,
                                                 const float* __restrict__ emb,
                                                 float* __restrict__ out,
                                                 float* __restrict__ ws) {
  __shared__ float hn_sh[1024];
  __shared__ int   ids[64];
  __shared__ int   nflag;
  __shared__ int   flist[64];
  __shared__ float xrow_sh[64];
  __shared__ float rsc[256];
  __shared__ int   rid[256];
  __shared__ float lred[256];

  const int t    = threadIdx.x;
  const int lane = t & 63;
  const int w    = t >> 6;        // wave id: 16 samples per wave
  const int quad = lane >> 4;
  const int l15  = lane & 15;
  const size_t m0 = (size_t)blockIdx.x * 64;

  if (t == 0) nflag = 0;
  #pragma unroll
  for (int i = 0; i < 4; ++i) hn_sh[t + i * 256] = ws[2048 + t + i * 256];

  // A fragments: sample row = m0 + w*16 + l15, k-window win: dims [win*32+quad*8, +8)
  bh8 ahi[2], alo[2];
  {
    const float* xr = xg + (m0 + w * 16 + l15) * 64 + quad * 8;
    #pragma unroll
    for (int win = 0; win < 2; ++win) {
      const v4f* p = (const v4f*)(xr + win * 32);
      v4f u0 = p[0], u1 = p[1];
      float xv[8] = {u0.x, u0.y, u0.z, u0.w, u1.x, u1.y, u1.z, u1.w};
      #pragma unroll
      for (int j = 0; j < 8; ++j) {
        unsigned short h = f2bf_rn(xv[j]);
        float hf = __uint_as_float((unsigned)h << 16);
        ahi[win][j] = (short)h;
        alo[win][j] = (short)f2bf_rn(xv[j] - hf);
      }
    }
  }
  __syncthreads();   // hn_sh + nflag ready

  const bh8* ehi = (const bh8*)(ws + EHI_F);   // 8 bh8 per code
  const bh8* elo = (const bh8*)(ws + ELO_F);

  float b1[4], b2[4]; int i1[4];
  #pragma unroll
  for (int i = 0; i < 4; ++i) { b1[i] = 3.4e38f; b2[i] = 3.4e38f; i1[i] = 0; }

  #pragma unroll 2
  for (int nt = 0; nt < 64; ++nt) {
    const int nc = nt * 16 + l15;          // this lane's code column
    const size_t cb = (size_t)nc * 8;
    bh8 bh0 = ehi[cb + quad];              // win0: k in [0,32)
    bh8 bh1 = ehi[cb + 4 + quad];          // win1: k in [32,64)
    bh8 bl0 = elo[cb + quad];
    bh8 bl1 = elo[cb + 4 + quad];
    v4f acc = {0.f, 0.f, 0.f, 0.f};
    acc = __builtin_amdgcn_mfma_f32_16x16x32_bf16(ahi[0], bh0, acc, 0, 0, 0);
    acc = __builtin_amdgcn_mfma_f32_16x16x32_bf16(ahi[1], bh1, acc, 0, 0, 0);
    acc = __builtin_amdgcn_mfma_f32_16x16x32_bf16(alo[0], bh0, acc, 0, 0, 0);
    acc = __builtin_amdgcn_mfma_f32_16x16x32_bf16(alo[1], bh1, acc, 0, 0, 0);
    acc = __builtin_amdgcn_mfma_f32_16x16x32_bf16(ahi[0], bl0, acc, 0, 0, 0);
    acc = __builtin_amdgcn_mfma_f32_16x16x32_bf16(ahi[1], bl1, acc, 0, 0, 0);
    float hnv = hn_sh[nc];                 // 16 banks, 4-lane same-addr broadcast
    #pragma unroll
    for (int i = 0; i < 4; ++i) {
      float sc = hnv - acc[i];
      bool lt = sc < b1[i];                // strict <: lower code wins ties per lane
      b2[i] = lt ? b1[i] : fminf(b2[i], sc);
      i1[i] = lt ? nc : i1[i];
      b1[i] = lt ? sc : b1[i];
    }
  }

  // cross-lane top-2 argmin butterfly within each quad's 16 lanes
  #pragma unroll
  for (int m = 1; m <= 8; m <<= 1) {
    #pragma unroll
    for (int i = 0; i < 4; ++i) {
      float o1 = __shfl_xor(b1[i], m);
      int   oi = __shfl_xor(i1[i], m);
      float o2 = __shfl_xor(b2[i], m);
      float loser = fmaxf(b1[i], o1);
      b2[i] = fminf(loser, fminf(b2[i], o2));
      bool take = (o1 < b1[i]) || (o1 == b1[i] && oi < i1[i]);
      b1[i] = take ? o1 : b1[i];
      i1[i] = take ? oi : i1[i];
    }
  }

  if (l15 == 0) {                          // one writer per quad: rows quad*4+i
    #pragma unroll
    for (int i = 0; i < 4; ++i) {
      int r = w * 16 + quad * 4 + i;
      ids[r] = i1[i];
      if (b2[i] - b1[i] < EPS_GAP) {       // near-tie: exact rescan needed
        int p = atomicAdd(&nflag, 1);
        flist[p] = r;
      }
    }
  }
  __syncthreads();

  // exact fp32 rescan of flagged rows (rare; same arithmetic as R7/R8)
  for (int f = 0; f < nflag; ++f) {
    int r = flist[f];
    if (t < 64) xrow_sh[t] = xg[(m0 + r) * 64 + t];
    __syncthreads();
    float bb = 3.4e38f; int bi = 0;
    #pragma unroll 1
    for (int cc = 0; cc < 4; ++cc) {
      int c = t * 4 + cc;                  // ascending codes within thread
      const float* ep = emb + (size_t)c * 64;
      float dot = 0.f;
      #pragma unroll
      for (int k = 0; k < 64; ++k) dot = fmaf(xrow_sh[k], ep[k], dot);
      float sc = hn_sh[c] - dot;
      if (sc < bb) { bb = sc; bi = c; }
    }
    rsc[t] = bb; rid[t] = bi;
    __syncthreads();
    for (int off = 128; off > 0; off >>= 1) {
      if (t < off) {
        float so = rsc[t + off]; int io = rid[t + off];
        if (so < rsc[t] || (so == rsc[t] && io < rid[t])) { rsc[t] = so; rid[t] = io; }
      }
      __syncthreads();
    }
    if (t == 0) ids[r] = rid[0];
    __syncthreads();
  }

  if (t < 64) atomicAdd((unsigned int*)ws + ids[t], 1u);

  // ---- fused store phase: quantized + commitment loss (exact fp32) ----
  float lsum = 0.f;
  {
    float* qblk = out + QUANT_OFF + m0 * 64;
    const float* xblk = xg + m0 * 64;
    #pragma unroll 1
    for (int it = 0; it < 16; ++it) {
      int fidx = it * 256 + t;
      int r = fidx >> 6, d = fidx & 63;
      float ev = emb[((size_t)ids[r] << 6) + d];
      float xv = xblk[fidx];
      float dx = ev - xv;
      lsum = fmaf(dx, dx, lsum);
      __builtin_nontemporal_store(xv + dx, qblk + fidx);  // x + (e-x): ref order
    }
  }
  lred[t] = lsum;
  __syncthreads();
  #pragma unroll
  for (int off = 128; off > 0; off >>= 1) {
    if (t < off) lred[t] += lred[t + off];
    __syncthreads();
  }
  if (t == 0) atomicAdd(ws + 1024, lred[0]);

  // ---- one-hot encodings (64 rows x 1024) ----
  v2f* eblk = (v2f*)(out + ENC_OFF) + m0 * 512;
  #pragma unroll 1
  for (int r = 0; r < 64; ++r) {
    int hit = ids[r];                      // broadcast LDS read
    int hc  = hit >> 1;
    v2f one; one.x = (hit & 1) ? 0.0f : 1.0f; one.y = (hit & 1) ? 1.0f : 0.0f;
    v2f zer; zer.x = 0.0f; zer.y = 0.0f;
    v2f* rowp = eblk + (size_t)r * 512;
    __builtin_nontemporal_store((hc == t)       ? one : zer, rowp + t);
    __builtin_nontemporal_store((hc == t + 256) ? one : zer, rowp + t + 256);
  }
}

__global__ __launch_bounds__(256) void k_fin(float* __restrict__ out,
                                             const float* __restrict__ ws) {
  __shared__ float red[256];
  const unsigned int* counts = (const unsigned int*)ws;
  int t = threadIdx.x;
  float s = 0.0f;
  #pragma unroll
  for (int i = 0; i < 4; ++i) {
    float p = (float)counts[t + i * 256] * (1.0f / (float)N_IN);
    s += p * __logf(p + 1e-10f);
  }
  red[t] = s;
  __syncthreads();
  #pragma unroll
  for (int off = 128; off > 0; off >>= 1) {
    if (t < off) red[t] += red[t + off];
    __syncthreads();
  }
  if (t == 0) {
    out[PERP_OFF] = __expf(-red[0]);
    out[0] = 0.25f * ws[1024] * (1.0f / (float)(N_IN * D_EMB));
  }
}

extern "C" void kernel_launch(void* const* d_in, const int* in_sizes, int n_in,
                              void* d_out, int out_size, void* d_ws, size_t ws_size,
                              hipStream_t stream) {
  (void)in_sizes; (void)n_in; (void)out_size; (void)ws_size;
  const float* x   = (const float*)d_in[0];
  const float* emb = (const float*)d_in[1];
  float* out = (float*)d_out;
  float* ws  = (float*)d_ws;

  hipLaunchKernelGGL(k_prep, dim3(4),    dim3(256), 0, stream, emb, ws);
  hipLaunchKernelGGL(k_gemm, dim3(2048), dim3(256), 0, stream, x, emb, out, ws);
  hipLaunchKernelGGL(k_fin,  dim3(1),    dim3(256), 0, stream, out, ws);
}